// Round 16
// baseline (106.272 us; speedup 1.0000x reference)
//
#include <hip/hip_runtime.h>

typedef unsigned short u16;
typedef __bf16 bf16x8 __attribute__((ext_vector_type(8)));
typedef float f32x4 __attribute__((ext_vector_type(4)));

#define WEMD 400
#define RANK 396
#define NA   16384     // SEQ*BATCH
#define K2   448       // padded K for both gemms (7 tiles of 64 k-values)
#define BSTR 896       // byte stride of Wbf/Ubt/Tbt/H rows (448*2)
#define NBC  2500
#define NBCP 2560

// ---- ws layout (bytes) ----
#define OFF_WBF  0u                 // u16 [16416][448]
#define OFF_UBT  14708736u          // u16 [512][448]
#define OFF_TBT  15167488u          // u16 [512][448]
#define OFF_G    15626240u          // u16 G' fragment-packed, 2,293,760 B
#define OFF_H    17920000u          // u16 [16384][448]

// G' packed layout (u16 units):
//   idx = ((((tn_t*7 + kt)*2 + ks)*8 + rg)*64 + lane)*8 + j
//   maps to logical G(row = tn_t*128 + rg*16 + (lane&15),
//                    k   = kt*64 + ks*32 + (lane>>4)*8 + j)
// so big2's B-fragment (ks, rg=wn*4+cf) is 64 lanes x 16 B CONTIGUOUS.

__device__ __forceinline__ u16 f2bf(float f) {
  union { float f; unsigned u; } v; v.f = f;
  unsigned u = v.u;
  return (u16)((u + 0x7FFFu + ((u >> 16) & 1u)) >> 16);  // RNE
}

typedef __attribute__((address_space(3))) unsigned char lds_byte;
typedef __attribute__((address_space(1))) const unsigned char glob_byte;

__device__ __forceinline__ void gload16(const void* g, void* l) {
  __builtin_amdgcn_global_load_lds((glob_byte*)g, (lds_byte*)l, 16, 0, 0);
}

// ---------- fused prep: Wbf + Ubt/Tbt + packed G' ----------
__global__ __launch_bounds__(256) void prep_all(
    const float* __restrict__ word, const float* __restrict__ first,
    const float* __restrict__ U, const float* __restrict__ T,
    const float* __restrict__ tag, const float* __restrict__ V,
    const float* __restrict__ W,
    u16* __restrict__ Wbf, u16* __restrict__ Ubt, u16* __restrict__ Tbt,
    u16* __restrict__ Gp) {
  const int R0 = 16416 * 112;          // Wbf as float4 items (448/4 = 112 per row)
  const int R1 = 448 << 9;             // U/T transpose
  const int R2 = 20 * 7 * 2 * 8 * 64 * 8;  // G' items = 1,146,880
  const int total = R0 + R1 + R2;
  for (int i = blockIdx.x * 256 + threadIdx.x; i < total; i += gridDim.x * 256) {
    if (i < R0) {
      int r = i / 112, c4 = i - r * 112;
      ushort4 o = {0, 0, 0, 0};
      if (c4 < 100) {
        const float* src = (r < 32) ? (first + c4 * 4)
                                    : (word + (size_t)(r - 32) * WEMD + c4 * 4);
        float4 v = *(const float4*)src;
        o.x = f2bf(v.x); o.y = f2bf(v.y); o.z = f2bf(v.z); o.w = f2bf(v.w);
      }
      *(ushort4*)(Wbf + (size_t)r * K2 + c4 * 4) = o;
    } else if (i < R0 + R1) {
      int j = i - R0;
      int n = j & 511, k = j >> 9;
      u16 uo = 0, to = 0;
      if (n < RANK && k < WEMD) {
        uo = f2bf(U[(size_t)k * RANK + n]);
        to = f2bf(T[(size_t)k * RANK + n]);
      }
      Ubt[(size_t)n * K2 + k] = uo;
      Tbt[(size_t)n * K2 + k] = to;
    } else {
      int idx = i - R0 - R1;
      int j    = idx & 7;
      int lane = (idx >> 3) & 63;
      int rg   = (idx >> 9) & 7;
      int ks   = (idx >> 12) & 1;
      int rem  = idx >> 13;             // [0, 140)
      int kt   = rem % 7;
      int tn_t = rem / 7;
      int bc = tn_t * 128 + rg * 16 + (lane & 15);
      int k  = kt * 64 + ks * 32 + ((lane >> 4) << 3) + j;
      u16 g = 0;
      if (bc < NBC && k < RANK) {
        int b = bc / 50, c = bc - b * 50;
        float a2 = 0.f, a3 = 0.f;
        #pragma unroll
        for (int e = 0; e < 20; ++e) {
          a2 += tag[b * 20 + e] * V[e * RANK + k];
          a3 += tag[c * 20 + e] * W[e * RANK + k];
        }
        g = f2bf(a2 * a3);
      }
      Gp[idx] = g;
    }
  }
}

// ---------- H = (word@U) * (neighbor@T), bf16 out, stride 448 (R15-proven) ----------
__global__ __launch_bounds__(256) void gemm_h(const u16* __restrict__ Wbf,
                                              const u16* __restrict__ Ubt,
                                              const u16* __restrict__ Tbt,
                                              u16* __restrict__ H) {
  __shared__ __align__(16) u16 Ash[160 * 64];   // 20480 B
  __shared__ __align__(16) u16 Bu[128 * 64];    // 16384 B
  __shared__ __align__(16) u16 Bt[128 * 64];    // 16384 B
  const int tid = threadIdx.x;
  const int l = tid & 63, w = tid >> 6;
  const int wm = w >> 1, wn = w & 1;
  int bs = (int)blockIdx.x;
  bs = (bs & 7) * 64 + (bs >> 3);               // XCD swizzle, 512 % 8 == 0
  const int tm = (bs >> 2) * 128, tn = (bs & 3) * 128;

  f32x4 acc0[4][4] = {}, acc1[4][4] = {};

  const char* gA = (const char*)Wbf + (size_t)tm * BSTR;
  const char* gU = (const char*)Ubt + (size_t)tn * BSTR;
  const char* gT = (const char*)Tbt + (size_t)tn * BSTR;

  const int sw = (l & 7) << 4;

  for (int kt = 0; kt < 7; ++kt) {
    const int kb = kt * 128;
    #pragma unroll
    for (int q = 0; q < 5; ++q) {               // A: 160 rows x 128 B
      int P = tid * 16 + q * 4096;
      int row = P >> 7;
      int col = (P & 127) ^ ((row & 7) << 4);
      gload16(gA + (size_t)row * BSTR + kb + col, (char*)Ash + P);
    }
    #pragma unroll
    for (int q = 0; q < 4; ++q) {               // Bu/Bt: 128 rows x 128 B each
      int P = tid * 16 + q * 4096;
      int row = P >> 7;
      int col = (P & 127) ^ ((row & 7) << 4);
      gload16(gU + (size_t)row * BSTR + kb + col, (char*)Bu + P);
      gload16(gT + (size_t)row * BSTR + kb + col, (char*)Bt + P);
    }
    __syncthreads();
    #pragma unroll
    for (int ks = 0; ks < 2; ++ks) {
      const int csw = (ks * 64 + (l >> 4) * 16) ^ sw;
      bf16x8 a0[4], a1[4], bu[4], bt[4];
      #pragma unroll
      for (int i = 0; i < 4; ++i) {
        const int ra = wm * 64 + i * 16 + (l & 15);
        const int rb = wn * 64 + i * 16 + (l & 15);
        a1[i] = *(const bf16x8*)((const char*)Ash + (size_t)ra * 128 + csw);
        a0[i] = *(const bf16x8*)((const char*)Ash + (size_t)(ra + 32) * 128 + csw);
        bu[i] = *(const bf16x8*)((const char*)Bu + (size_t)rb * 128 + csw);
        bt[i] = *(const bf16x8*)((const char*)Bt + (size_t)rb * 128 + csw);
      }
      #pragma unroll
      for (int i = 0; i < 4; ++i)
        #pragma unroll
        for (int j = 0; j < 4; ++j) {
          acc0[i][j] = __builtin_amdgcn_mfma_f32_16x16x32_bf16(a0[i], bu[j], acc0[i][j], 0, 0, 0);
          acc1[i][j] = __builtin_amdgcn_mfma_f32_16x16x32_bf16(a1[i], bt[j], acc1[i][j], 0, 0, 0);
        }
    }
    __syncthreads();
  }

  const int r4 = (l >> 4) * 4, cc = l & 15;
  #pragma unroll
  for (int i = 0; i < 4; ++i)
    #pragma unroll
    for (int j = 0; j < 4; ++j) {
      const int col = tn + wn * 64 + j * 16 + cc;
      if (col < K2) {
        #pragma unroll
        for (int r = 0; r < 4; ++r) {
          const int rowg = tm + wm * 64 + i * 16 + r4 + r;
          H[(size_t)rowg * K2 + col] = f2bf(acc0[i][j][r] * acc1[i][j][r]);
        }
      }
    }
}

// ---------- out[16384,2500] = H @ G'^T : A-staged LDS + packed-B-direct ----------
// A side: R4-proven verbatim (gload16 + XOR swizzle + 2-barrier loop, 16 KB).
// B side: fragment-packed G' -> each B frag is a fully-coalesced 1 KB/wave
// global load from L2 into registers (fixes R8's 4x fetch amplification).
// No B LDS, no B swizzle, no new sync: __syncthreads' vmcnt(0) drain orders
// the B reg-loads exactly like the A staging.
__global__ __launch_bounds__(256, 3) void gemm_big6(const u16* __restrict__ H,
                                                    const u16* __restrict__ Gp,
                                                    float* __restrict__ out) {
  __shared__ u16 lds[8192];       // A only: 16 KiB
  char* ldsb = (char*)lds;
  const int tid = threadIdx.x;
  const int lane = tid & 63, wid = tid >> 6;
  const int wm = wid >> 1, wn = wid & 1;

  int bs = (int)blockIdx.x;
  bs = (bs & 7) * 320 + (bs >> 3);              // XCD swizzle, 2560 % 8 == 0
  const int tm = (bs / 20) * 128;
  const int tn_t = bs % 20;
  const int tn = tn_t * 128;

  const char* gH = (const char*)H + (size_t)tm * BSTR;
  // per-(kt) B base: tile stride 7*16384 B; kt stride 16384 B; lane offset 16 B
  const char* gB = (const char*)Gp + (size_t)tn_t * 7 * 16384 + lane * 16;

  int sP[4], sR[4], sC[4];
  #pragma unroll
  for (int q = 0; q < 4; ++q) {
    int P = tid * 16 + q * 4096;
    int L = P ^ (((P >> 7) & 7) << 4);
    sP[q] = P; sR[q] = L >> 7; sC[q] = L & 127;
  }
  const int arow = (lane & 15) * 128;
  const int sw = (lane & 7) << 4;

  f32x4 acc[4][4] = {};

  for (int kt = 0; kt < 7; ++kt) {
    const int kb = kt * 128;
    #pragma unroll
    for (int q = 0; q < 4; ++q)
      gload16(gH + (size_t)sR[q] * BSTR + kb + sC[q], ldsb + sP[q]);
    // B fragments: coalesced reg-loads, frag (ks, rg=wn*4+cf) at
    // ((kt*2+ks)*8 + rg)*1024 + lane*16
    bf16x8 b[2][4];
    #pragma unroll
    for (int ks = 0; ks < 2; ++ks)
      #pragma unroll
      for (int cf = 0; cf < 4; ++cf)
        b[ks][cf] = *(const bf16x8*)(gB + (size_t)(((kt * 2 + ks) * 8 + wn * 4 + cf)) * 1024);
    __syncthreads();                            // drains vmcnt: A in LDS, B in regs
    #pragma unroll
    for (int ks = 0; ks < 2; ++ks) {
      const int csw = (ks * 64 + (lane >> 4) * 16) ^ sw;
      bf16x8 a[4];
      #pragma unroll
      for (int rf = 0; rf < 4; ++rf)
        a[rf] = *(const bf16x8*)(ldsb + wm * 8192 + rf * 2048 + arow + csw);
      #pragma unroll
      for (int rf = 0; rf < 4; ++rf)
        #pragma unroll
        for (int cf = 0; cf < 4; ++cf)
          acc[rf][cf] = __builtin_amdgcn_mfma_f32_16x16x32_bf16(a[rf], b[ks][cf], acc[rf][cf], 0, 0, 0);
    }
    __syncthreads();
  }

  const int r4 = (lane >> 4) * 4, cc = lane & 15;
  const int rbase = tm + wm * 64 + r4;
  const int cbase = tn + wn * 64 + cc;
  #pragma unroll
  for (int rf = 0; rf < 4; ++rf)
    #pragma unroll
    for (int cf = 0; cf < 4; ++cf) {
      const int col = cbase + cf * 16;
      if (col < NBC) {
        #pragma unroll
        for (int rr = 0; rr < 4; ++rr)
          out[(size_t)(rbase + rf * 16 + rr) * NBC + col] = acc[rf][cf][rr];
      }
    }
}

extern "C" void kernel_launch(void* const* d_in, const int* in_sizes, int n_in,
                              void* d_out, int out_size, void* d_ws, size_t ws_size,
                              hipStream_t stream) {
  const float* word  = (const float*)d_in[0];
  const float* tag   = (const float*)d_in[1];
  const float* Tm    = (const float*)d_in[2];
  const float* Um    = (const float*)d_in[3];
  const float* Vm    = (const float*)d_in[4];
  const float* Wm    = (const float*)d_in[5];
  const float* first = (const float*)d_in[6];
  float* out = (float*)d_out;
  char* ws = (char*)d_ws;

  u16*   Wbf = (u16*)(ws + OFF_WBF);
  u16*   Ubt = (u16*)(ws + OFF_UBT);
  u16*   Tbt = (u16*)(ws + OFF_TBT);
  u16*   Gp  = (u16*)(ws + OFF_G);
  u16*   H   = (u16*)(ws + OFF_H);

  hipLaunchKernelGGL(prep_all, dim3(2048), dim3(256), 0, stream,
                     word, first, Um, Tm, tag, Vm, Wm, Wbf, Ubt, Tbt, Gp);
  hipLaunchKernelGGL(gemm_h,   dim3(512), dim3(256), 0, stream, Wbf, Ubt, Tbt, H);
  hipLaunchKernelGGL(gemm_big6, dim3(2560), dim3(256), 0, stream, H, Gp, out);
}

// Round 17
// 102.160 us; speedup vs baseline: 1.0403x; 1.0403x over previous
//
#include <hip/hip_runtime.h>

typedef unsigned short u16;
typedef __bf16 bf16x8 __attribute__((ext_vector_type(8)));
typedef float f32x4 __attribute__((ext_vector_type(4)));

#define WEMD 400
#define RANK 396
#define NA   16384     // SEQ*BATCH
#define K2   448       // padded K for BOTH gemms (7 tiles of 64 k-values)
#define BSTR 896       // byte stride of Wbf/Ubt/Tbt/G/H rows (448*2)
#define NBC  2500
#define NBCP 2560

// ---- ws layout (bytes) ----
#define OFF_WBF  0u                 // u16 [16416][448] = 14,708,736
#define OFF_UBT  14708736u          // u16 [512][448]   =    458,752
#define OFF_TBT  15167488u          // u16 [512][448]
#define OFF_G    15626240u          // u16 [2560][448]  =  2,293,760
#define OFF_H    17920000u          // u16 [16384][448] = 14,680,064 (total ~32.6 MB)

__device__ __forceinline__ u16 f2bf(float f) {
  union { float f; unsigned u; } v; v.f = f;
  unsigned u = v.u;
  return (u16)((u + 0x7FFFu + ((u >> 16) & 1u)) >> 16);  // RNE
}

typedef __attribute__((address_space(3))) unsigned char lds_byte;
typedef __attribute__((address_space(1))) const unsigned char glob_byte;

__device__ __forceinline__ void gload16(const void* g, void* l) {
  __builtin_amdgcn_global_load_lds((glob_byte*)g, (lds_byte*)l, 16, 0, 0);
}

// ---------- fused prep: Wbf + Ubt/Tbt + G, all strided 448 (R15-proven) ----------
__global__ __launch_bounds__(256) void prep_all(
    const float* __restrict__ word, const float* __restrict__ first,
    const float* __restrict__ U, const float* __restrict__ T,
    const float* __restrict__ tag, const float* __restrict__ V,
    const float* __restrict__ W,
    u16* __restrict__ Wbf, u16* __restrict__ Ubt, u16* __restrict__ Tbt,
    u16* __restrict__ G) {
  const int R0 = 16416 * 112;          // Wbf as float4 items (448/4 = 112 per row)
  const int R1 = 448 << 9;             // U/T transpose: k = j>>9 (0..447), n = j&511
  const int R2 = NBCP * K2;            // G items
  const int total = R0 + R1 + R2;
  for (int i = blockIdx.x * 256 + threadIdx.x; i < total; i += gridDim.x * 256) {
    if (i < R0) {
      int r = i / 112, c4 = i - r * 112;
      ushort4 o = {0, 0, 0, 0};
      if (c4 < 100) {
        const float* src = (r < 32) ? (first + c4 * 4)
                                    : (word + (size_t)(r - 32) * WEMD + c4 * 4);
        float4 v = *(const float4*)src;
        o.x = f2bf(v.x); o.y = f2bf(v.y); o.z = f2bf(v.z); o.w = f2bf(v.w);
      }
      *(ushort4*)(Wbf + (size_t)r * K2 + c4 * 4) = o;
    } else if (i < R0 + R1) {
      int j = i - R0;
      int n = j & 511, k = j >> 9;
      u16 uo = 0, to = 0;
      if (n < RANK && k < WEMD) {
        uo = f2bf(U[(size_t)k * RANK + n]);
        to = f2bf(T[(size_t)k * RANK + n]);
      }
      Ubt[(size_t)n * K2 + k] = uo;
      Tbt[(size_t)n * K2 + k] = to;
    } else {
      int j = i - R0 - R1;
      int bc = j / K2, k = j - bc * K2;
      u16 g = 0;
      if (bc < NBC && k < RANK) {
        int b = bc / 50, c = bc - b * 50;
        float a2 = 0.f, a3 = 0.f;
        #pragma unroll
        for (int e = 0; e < 20; ++e) {
          a2 += tag[b * 20 + e] * V[e * RANK + k];
          a3 += tag[c * 20 + e] * W[e * RANK + k];
        }
        g = f2bf(a2 * a3);
      }
      G[(size_t)bc * K2 + k] = g;
    }
  }
}

// ---------- H = (word@U) * (neighbor@T), bf16 out, stride 448 (R15-proven) ----------
// big2's LDS layout transplanted: [row][128B] tiles, XOR swizzle
// phys = logical ^ ((row&7)<<4) on both sides, BK=128B (64 k) -> 7
// barrier-pairs, conflict-free ds_read_b128. Shared-A: stage Wbf rows
// [tm, tm+160) once; a1 at row r, a0 at r+32. XCD swizzle on grid.
__global__ __launch_bounds__(256) void gemm_h(const u16* __restrict__ Wbf,
                                              const u16* __restrict__ Ubt,
                                              const u16* __restrict__ Tbt,
                                              u16* __restrict__ H) {
  __shared__ __align__(16) u16 Ash[160 * 64];   // 20480 B
  __shared__ __align__(16) u16 Bu[128 * 64];    // 16384 B
  __shared__ __align__(16) u16 Bt[128 * 64];    // 16384 B
  const int tid = threadIdx.x;
  const int l = tid & 63, w = tid >> 6;
  const int wm = w >> 1, wn = w & 1;
  int bs = (int)blockIdx.x;
  bs = (bs & 7) * 64 + (bs >> 3);               // XCD swizzle, 512 % 8 == 0
  const int tm = (bs >> 2) * 128, tn = (bs & 3) * 128;

  f32x4 acc0[4][4] = {}, acc1[4][4] = {};

  const char* gA = (const char*)Wbf + (size_t)tm * BSTR;
  const char* gU = (const char*)Ubt + (size_t)tn * BSTR;
  const char* gT = (const char*)Tbt + (size_t)tn * BSTR;

  const int sw = (l & 7) << 4;

  for (int kt = 0; kt < 7; ++kt) {
    const int kb = kt * 128;
    #pragma unroll
    for (int q = 0; q < 5; ++q) {               // A: 160 rows x 128 B
      int P = tid * 16 + q * 4096;
      int row = P >> 7;
      int col = (P & 127) ^ ((row & 7) << 4);
      gload16(gA + (size_t)row * BSTR + kb + col, (char*)Ash + P);
    }
    #pragma unroll
    for (int q = 0; q < 4; ++q) {               // Bu/Bt: 128 rows x 128 B each
      int P = tid * 16 + q * 4096;
      int row = P >> 7;
      int col = (P & 127) ^ ((row & 7) << 4);
      gload16(gU + (size_t)row * BSTR + kb + col, (char*)Bu + P);
      gload16(gT + (size_t)row * BSTR + kb + col, (char*)Bt + P);
    }
    __syncthreads();
    #pragma unroll
    for (int ks = 0; ks < 2; ++ks) {
      const int csw = (ks * 64 + (l >> 4) * 16) ^ sw;
      bf16x8 a0[4], a1[4], bu[4], bt[4];
      #pragma unroll
      for (int i = 0; i < 4; ++i) {
        const int ra = wm * 64 + i * 16 + (l & 15);
        const int rb = wn * 64 + i * 16 + (l & 15);
        a1[i] = *(const bf16x8*)((const char*)Ash + (size_t)ra * 128 + csw);
        a0[i] = *(const bf16x8*)((const char*)Ash + (size_t)(ra + 32) * 128 + csw);
        bu[i] = *(const bf16x8*)((const char*)Bu + (size_t)rb * 128 + csw);
        bt[i] = *(const bf16x8*)((const char*)Bt + (size_t)rb * 128 + csw);
      }
      #pragma unroll
      for (int i = 0; i < 4; ++i)
        #pragma unroll
        for (int j = 0; j < 4; ++j) {
          acc0[i][j] = __builtin_amdgcn_mfma_f32_16x16x32_bf16(a0[i], bu[j], acc0[i][j], 0, 0, 0);
          acc1[i][j] = __builtin_amdgcn_mfma_f32_16x16x32_bf16(a1[i], bt[j], acc1[i][j], 0, 0, 0);
        }
    }
    __syncthreads();
  }

  const int r4 = (l >> 4) * 4, cc = l & 15;
  #pragma unroll
  for (int i = 0; i < 4; ++i)
    #pragma unroll
    for (int j = 0; j < 4; ++j) {
      const int col = tn + wn * 64 + j * 16 + cc;
      if (col < K2) {
        #pragma unroll
        for (int r = 0; r < 4; ++r) {
          const int rowg = tm + wm * 64 + i * 16 + r4 + r;
          H[(size_t)rowg * K2 + col] = f2bf(acc0[i][j][r] * acc1[i][j][r]);
        }
      }
    }
}

// ---------- out[16384,2500] = H[.,448] @ G^T (R4/R13-proven, FROZEN) ----------
// 128x128 tile, BK=64, 256 thr (4 waves 2x2), single-buffered 32 KiB LDS ->
// 3 blocks/CU; co-residency provides the overlap (m114). Validated swizzle:
// physical = logical ^ ((row&7)<<4), both sides.
// 10 schedule/tile/B-path variants all lost to this structure — FROZEN.
__global__ __launch_bounds__(256, 3) void gemm_big2(const u16* __restrict__ H,
                                                    const u16* __restrict__ G,
                                                    float* __restrict__ out) {
  __shared__ u16 lds[2 * 8192];   // A 16 KiB + B 16 KiB
  char* ldsb = (char*)lds;
  const int tid = threadIdx.x;
  const int lane = tid & 63, wid = tid >> 6;
  const int wm = wid >> 1, wn = wid & 1;

  int bs = (int)blockIdx.x;
  bs = (bs & 7) * 320 + (bs >> 3);              // XCD swizzle, 2560 % 8 == 0
  const int tm = (bs / 20) * 128, tn = (bs % 20) * 128;

  const char* gH = (const char*)H + (size_t)tm * BSTR;
  const char* gG = (const char*)G + (size_t)tn * BSTR;

  int sP[4], sR[4], sC[4];
  #pragma unroll
  for (int q = 0; q < 4; ++q) {
    int P = tid * 16 + q * 4096;
    int L = P ^ (((P >> 7) & 7) << 4);
    sP[q] = P; sR[q] = L >> 7; sC[q] = L & 127;
  }
  const int arow = (lane & 15) * 128;
  const int sw = (lane & 7) << 4;

  f32x4 acc[4][4] = {};

  for (int kt = 0; kt < 7; ++kt) {
    const int kb = kt * 128;
    #pragma unroll
    for (int q = 0; q < 4; ++q) {
      gload16(gH + (size_t)sR[q] * BSTR + kb + sC[q], ldsb + sP[q]);
      gload16(gG + (size_t)sR[q] * BSTR + kb + sC[q], ldsb + 16384 + sP[q]);
    }
    __syncthreads();
    #pragma unroll
    for (int ks = 0; ks < 2; ++ks) {
      const int csw = (ks * 64 + (lane >> 4) * 16) ^ sw;
      bf16x8 a[4], b[4];
      #pragma unroll
      for (int rf = 0; rf < 4; ++rf)
        a[rf] = *(const bf16x8*)(ldsb + wm * 8192 + rf * 2048 + arow + csw);
      #pragma unroll
      for (int cf = 0; cf < 4; ++cf)
        b[cf] = *(const bf16x8*)(ldsb + 16384 + wn * 8192 + cf * 2048 + arow + csw);
      #pragma unroll
      for (int rf = 0; rf < 4; ++rf)
        #pragma unroll
        for (int cf = 0; cf < 4; ++cf)
          acc[rf][cf] = __builtin_amdgcn_mfma_f32_16x16x32_bf16(a[rf], b[cf], acc[rf][cf], 0, 0, 0);
    }
    __syncthreads();
  }

  const int r4 = (lane >> 4) * 4, cc = lane & 15;
  const int rbase = tm + wm * 64 + r4;
  const int cbase = tn + wn * 64 + cc;
  #pragma unroll
  for (int rf = 0; rf < 4; ++rf)
    #pragma unroll
    for (int cf = 0; cf < 4; ++cf) {
      const int col = cbase + cf * 16;
      if (col < NBC) {
        #pragma unroll
        for (int rr = 0; rr < 4; ++rr)
          out[(size_t)(rbase + rf * 16 + rr) * NBC + col] = acc[rf][cf][rr];
      }
    }
}

extern "C" void kernel_launch(void* const* d_in, const int* in_sizes, int n_in,
                              void* d_out, int out_size, void* d_ws, size_t ws_size,
                              hipStream_t stream) {
  const float* word  = (const float*)d_in[0];
  const float* tag   = (const float*)d_in[1];
  const float* Tm    = (const float*)d_in[2];
  const float* Um    = (const float*)d_in[3];
  const float* Vm    = (const float*)d_in[4];
  const float* Wm    = (const float*)d_in[5];
  const float* first = (const float*)d_in[6];
  float* out = (float*)d_out;
  char* ws = (char*)d_ws;

  u16*   Wbf = (u16*)(ws + OFF_WBF);
  u16*   Ubt = (u16*)(ws + OFF_UBT);
  u16*   Tbt = (u16*)(ws + OFF_TBT);
  u16*   G   = (u16*)(ws + OFF_G);
  u16*   H   = (u16*)(ws + OFF_H);

  hipLaunchKernelGGL(prep_all, dim3(2048), dim3(256), 0, stream,
                     word, first, Um, Tm, tag, Vm, Wm, Wbf, Ubt, Tbt, G);
  hipLaunchKernelGGL(gemm_h,   dim3(512), dim3(256), 0, stream, Wbf, Ubt, Tbt, H);
  hipLaunchKernelGGL(gemm_big2, dim3(2560), dim3(256), 0, stream, H, G, out);
}